// Round 9
// baseline (815.072 us; speedup 1.0000x reference)
//
#include <hip/hip_runtime.h>
#include <hip/hip_bf16.h>

typedef __attribute__((ext_vector_type(8))) short short8;
typedef __attribute__((ext_vector_type(4))) float f32x4;
typedef __attribute__((ext_vector_type(4))) unsigned uint4v;

#define NMODEL 24
#define DIN    495
#define KP     512
#define HID    64
#define NLAY   5

__device__ __forceinline__ short bf16r(float f) {
    unsigned u = __float_as_uint(f);
    u += 0x7fffu + ((u >> 16) & 1u);          // round-to-nearest-even
    return (short)(u >> 16);
}
__device__ __forceinline__ float bf16f(short s) {
    return __uint_as_float(((unsigned)(unsigned short)s) << 16);
}
// packed f32->bf16: one VALU op for two elements (gfx950 v_cvt_pk_bf16_f32)
__device__ __forceinline__ unsigned pkbf16(float lo, float hi) {
    unsigned r;
    asm("v_cvt_pk_bf16_f32 %0, %1, %2" : "=v"(r) : "v"(lo), "v"(hi));
    return r;
}
// pack two f32x4 accumulator fragments into one MFMA B-fragment (short8)
__device__ __forceinline__ short8 pack2(f32x4 a, f32x4 b) {
    uint4v w;
    w[0] = pkbf16(a[0], a[1]);
    w[1] = pkbf16(a[2], a[3]);
    w[2] = pkbf16(b[0], b[1]);
    w[3] = pkbf16(b[2], b[3]);
    return __builtin_bit_cast(short8, w);
}

struct __attribute__((packed, aligned(4))) f4a { float v[4]; };

// ---------------------------------------------------------------------------
// Weight pre-conversion to bf16 in MFMA-fragment-friendly layouts.
//   wib[m][kb][hout][t]  = W_in[m][kb*8+t][hout]          (k padded 495->512)
//   whb[m][l][kb][hout][t] = W_h[m][l][pi(kb,t)][hout]    (pi bakes the C->B
//     lane-group relabeling of the hidden-in axis)
// ---------------------------------------------------------------------------
__global__ void dg_convert(const float* __restrict__ W_in,
                           const float* __restrict__ W_h,
                           short* __restrict__ wib, short* __restrict__ whb) {
    int idx = blockIdx.x * 256 + threadIdx.x;
    if (idx < NMODEL * 64 * HID * 8) {
        int t    = idx & 7;
        int hout = (idx >> 3) & 63;
        int kb   = (idx >> 9) & 63;
        int m    = idx >> 15;
        int k    = kb * 8 + t;
        float v  = (k < DIN) ? W_in[((size_t)m * DIN + k) * HID + hout] : 0.f;
        wib[idx] = bf16r(v);
    }
    if (idx < NMODEL * NLAY * 8 * HID * 8) {
        int t    = idx & 7;
        int hout = (idx >> 3) & 63;
        int kb   = (idx >> 9) & 7;     // kb = 4*s + g
        int ml   = idx >> 12;          // m*5 + l
        int pk   = 16 * (2 * (kb >> 2) + (t >> 2)) + 4 * (kb & 3) + (t & 3);
        float v  = W_h[((size_t)ml * HID + pk) * HID + hout];
        whb[idx] = bf16r(v);
    }
}

// ---------------------------------------------------------------------------
// Fused kernel. Block = 512 threads (8 waves), 64 rows of x staged in LDS
// (bf16, XOR-swizzled). Each wave owns a 32-row half-tile and processes its
// 6 models as 3 INTERLEAVED PAIRS (m, m+1): two independent load->MFMA
// chains per wave, so stream B's weight-load latency hides under stream A's
// MFMA/VALU and vice versa (dual-stream ILP — no cross-iteration register
// carries, everything constant-indexed, nothing can demote to scratch).
// Residual is applied via linearity: tanh(wo·(h5+h0)+b) = tanh(wo·h5 +
// wo·h0 + b); the scalar wo·h0 partial (2 regs/model) replaces the 16-reg
// packed h0 copy, keeping peak live regs ~125 <= 128.
// 64KB LDS -> 2 blocks/CU -> 16 waves/CU (4/SIMD).
// ---------------------------------------------------------------------------
__global__ __launch_bounds__(512, 4) void dg_main(
    const float* __restrict__ x,
    const short* __restrict__ wib, const short* __restrict__ whb,
    const float* __restrict__ b_in, const float* __restrict__ b_h,
    const float* __restrict__ W_out, const float* __restrict__ b_out,
    float* __restrict__ out) {

    __shared__ short xs[64 * KP];            // 64 KB

    const int tid  = threadIdx.x;
    const int lane = tid & 63;
    const int w    = tid >> 6;               // wave 0..7
    const int lrow = lane & 15;
    const int g    = lane >> 4;              // lane group 0..3
    const int rowbase = blockIdx.x * 64;
    const int pair = w >> 1;                 // 0..3: model group
    const int hf   = w & 1;                  // row half within the tile
    const int rbase = hf * 32;

    // ---- stage x tile -> LDS as bf16, swizzled, zero-padded k>=495 ----
    for (int i = 0; i < 8; ++i) {
        int r  = i * 8 + w;
        int k0 = lane * 8;
        const float* xr = x + (size_t)(rowbase + r) * DIN + k0;
        uint4v vw;
        if (k0 + 8 <= DIN) {                 // lanes 0..60: fast vector path
            f4a a = *(const f4a*)xr;
            f4a b = *(const f4a*)(xr + 4);
            vw[0] = pkbf16(a.v[0], a.v[1]);
            vw[1] = pkbf16(a.v[2], a.v[3]);
            vw[2] = pkbf16(b.v[0], b.v[1]);
            vw[3] = pkbf16(b.v[2], b.v[3]);
        } else {                             // lanes 61..63: guarded tail
            float f[8];
#pragma unroll
            for (int j = 0; j < 8; ++j) f[j] = (k0 + j < DIN) ? xr[j] : 0.f;
            vw[0] = pkbf16(f[0], f[1]);
            vw[1] = pkbf16(f[2], f[3]);
            vw[2] = pkbf16(f[4], f[5]);
            vw[3] = pkbf16(f[6], f[7]);
        }
        int byte = (r * (KP * 2) + k0 * 2) ^ ((r & 7) << 4);
        *(short8*)((char*)xs + byte) = __builtin_bit_cast(short8, vw);
    }
    __syncthreads();

    // ---- 3 model-duos per wave, no further synchronization ----
#pragma unroll 1
    for (int duo = 0; duo < 3; ++duo) {
        const int m0 = pair * 6 + duo * 2;
        const int m1 = m0 + 1;

        // ---------------- input projection: C[hout 64][row 32], K = 512
        f32x4 accA[4][2], accB[4][2];         // [icf(hout/16)][rf(row/16)]
#pragma unroll
        for (int a = 0; a < 4; ++a)
#pragma unroll
            for (int b = 0; b < 2; ++b) {
                accA[a][b] = (f32x4)0.0f;
                accB[a][b] = (f32x4)0.0f;
            }

        const short8* wA0 = (const short8*)wib + (size_t)m0 * 64 * 64;
        const short8* wA1 = (const short8*)wib + (size_t)m1 * 64 * 64;
#pragma unroll 2
        for (int skt = 0; skt < 16; ++skt) {
            const int kb = skt * 4 + g;
            short8 bfr[2];                    // x fragments shared by A and B
#pragma unroll
            for (int rf = 0; rf < 2; ++rf) {
                int r = rbase + rf * 16 + lrow;
                int byte = (r * (KP * 2) + skt * 64 + g * 16) ^ ((r & 7) << 4);
                bfr[rf] = *(const short8*)((const char*)xs + byte);
            }
            short8 fA[4], fB[4];
#pragma unroll
            for (int icf = 0; icf < 4; ++icf)
                fA[icf] = wA0[(size_t)kb * 64 + icf * 16 + lrow];
#pragma unroll
            for (int icf = 0; icf < 4; ++icf)
#pragma unroll
                for (int rf = 0; rf < 2; ++rf)
                    accA[icf][rf] = __builtin_amdgcn_mfma_f32_16x16x32_bf16(
                        fA[icf], bfr[rf], accA[icf][rf], 0, 0, 0);
#pragma unroll
            for (int icf = 0; icf < 4; ++icf)
                fB[icf] = wA1[(size_t)kb * 64 + icf * 16 + lrow];
#pragma unroll
            for (int icf = 0; icf < 4; ++icf)
#pragma unroll
                for (int rf = 0; rf < 2; ++rf)
                    accB[icf][rf] = __builtin_amdgcn_mfma_f32_16x16x32_bf16(
                        fB[icf], bfr[rf], accB[icf][rf], 0, 0, 0);
        }

        // + b_in  (h0 is NOT relu'd)
        const float* bi0 = b_in + m0 * HID;
        const float* bi1 = b_in + m1 * HID;
#pragma unroll
        for (int icf = 0; icf < 4; ++icf) {
            f32x4 bv0 = *(const f32x4*)(bi0 + icf * 16 + g * 4);
            f32x4 bv1 = *(const f32x4*)(bi1 + icf * 16 + g * 4);
#pragma unroll
            for (int rf = 0; rf < 2; ++rf) {
                accA[icf][rf] += bv0;
                accB[icf][rf] += bv1;
            }
        }

        // head partial from h0 (fp32, per-lane 16-elem slice; shuffles deferred)
        const float* wo0 = W_out + m0 * HID;
        const float* wo1 = W_out + m1 * HID;
        float hpA[2] = {0.f, 0.f}, hpB[2] = {0.f, 0.f};
#pragma unroll
        for (int icf = 0; icf < 4; ++icf) {
            f32x4 wv0 = *(const f32x4*)(wo0 + icf * 16 + g * 4);
            f32x4 wv1 = *(const f32x4*)(wo1 + icf * 16 + g * 4);
#pragma unroll
            for (int rf = 0; rf < 2; ++rf)
#pragma unroll
                for (int j = 0; j < 4; ++j) {
                    hpA[rf] += wv0[j] * accA[icf][rf][j];
                    hpB[rf] += wv1[j] * accB[icf][rf][j];
                }
        }

        // pack h0 -> layer-1 input fragments (hc owns the packed h0)
        short8 hcA[2][2], hcB[2][2];          // [s][rf]
#pragma unroll
        for (int s = 0; s < 2; ++s)
#pragma unroll
            for (int rf = 0; rf < 2; ++rf) {
                hcA[s][rf] = pack2(accA[2 * s][rf], accA[2 * s + 1][rf]);
                hcB[s][rf] = pack2(accB[2 * s][rf], accB[2 * s + 1][rf]);
            }

        // ---------------- 5 hidden layers, dual-stream interleave
        const short8* wH0 = (const short8*)whb + (size_t)m0 * NLAY * 8 * 64;
        const short8* wH1 = (const short8*)whb + (size_t)m1 * NLAY * 8 * 64;
        f32x4 haA[4][2], haB[4][2];
#pragma unroll 1
        for (int l = 0; l < NLAY; ++l) {
#pragma unroll
            for (int a = 0; a < 4; ++a)
#pragma unroll
                for (int b = 0; b < 2; ++b) {
                    haA[a][b] = (f32x4)0.0f;
                    haB[a][b] = (f32x4)0.0f;
                }
#pragma unroll
            for (int s = 0; s < 2; ++s) {
                const int kb = 4 * s + g;
                short8 fA[4], fB[4];
#pragma unroll
                for (int icf = 0; icf < 4; ++icf)
                    fA[icf] = wH0[(size_t)(l * 8 + kb) * 64 + icf * 16 + lrow];
#pragma unroll
                for (int icf = 0; icf < 4; ++icf)
#pragma unroll
                    for (int rf = 0; rf < 2; ++rf)
                        haA[icf][rf] = __builtin_amdgcn_mfma_f32_16x16x32_bf16(
                            fA[icf], hcA[s][rf], haA[icf][rf], 0, 0, 0);
#pragma unroll
                for (int icf = 0; icf < 4; ++icf)
                    fB[icf] = wH1[(size_t)(l * 8 + kb) * 64 + icf * 16 + lrow];
#pragma unroll
                for (int icf = 0; icf < 4; ++icf)
#pragma unroll
                    for (int rf = 0; rf < 2; ++rf)
                        haB[icf][rf] = __builtin_amdgcn_mfma_f32_16x16x32_bf16(
                            fB[icf], hcB[s][rf], haB[icf][rf], 0, 0, 0);
            }
            // bias + relu (A first — hides B's trailing MFMA latency)
            const float* bh0 = b_h + (size_t)(m0 * NLAY + l) * HID;
            const float* bh1 = b_h + (size_t)(m1 * NLAY + l) * HID;
#pragma unroll
            for (int icf = 0; icf < 4; ++icf) {
                f32x4 bv = *(const f32x4*)(bh0 + icf * 16 + g * 4);
#pragma unroll
                for (int rf = 0; rf < 2; ++rf)
#pragma unroll
                    for (int j = 0; j < 4; ++j)
                        haA[icf][rf][j] = fmaxf(haA[icf][rf][j] + bv[j], 0.f);
            }
#pragma unroll
            for (int icf = 0; icf < 4; ++icf) {
                f32x4 bv = *(const f32x4*)(bh1 + icf * 16 + g * 4);
#pragma unroll
                for (int rf = 0; rf < 2; ++rf)
#pragma unroll
                    for (int j = 0; j < 4; ++j)
                        haB[icf][rf][j] = fmaxf(haB[icf][rf][j] + bv[j], 0.f);
            }
            if (l != NLAY - 1) {
#pragma unroll
                for (int s = 0; s < 2; ++s)
#pragma unroll
                    for (int rf = 0; rf < 2; ++rf) {
                        hcA[s][rf] = pack2(haA[2 * s][rf], haA[2 * s + 1][rf]);
                        hcB[s][rf] = pack2(haB[2 * s][rf], haB[2 * s + 1][rf]);
                    }
            }
        }

        // ---------------- head: wo·h5 + (wo·h0 partial) + b_out, tanh, store
        const float bo0 = b_out[m0];
        const float bo1 = b_out[m1];
#pragma unroll
        for (int rf = 0; rf < 2; ++rf) {
            float sA = hpA[rf], sB = hpB[rf];
#pragma unroll
            for (int icf = 0; icf < 4; ++icf) {
                f32x4 wv0 = *(const f32x4*)(wo0 + icf * 16 + g * 4);
                f32x4 wv1 = *(const f32x4*)(wo1 + icf * 16 + g * 4);
#pragma unroll
                for (int j = 0; j < 4; ++j) {
                    sA += haA[icf][rf][j] * wv0[j];
                    sB += haB[icf][rf][j] * wv1[j];
                }
            }
            sA += __shfl_xor(sA, 16);
            sA += __shfl_xor(sA, 32);
            sB += __shfl_xor(sB, 16);
            sB += __shfl_xor(sB, 32);
            sA += bo0;
            sB += bo1;
            float eA = __expf(2.f * sA);               // overflow-safe tanh
            float eB = __expf(2.f * sB);
            float oA = 1.f - 2.f / (eA + 1.f);
            float oB = 1.f - 2.f / (eB + 1.f);
            if (g == 0) {
                size_t row = (size_t)(rowbase + rbase + rf * 16 + lrow);
                out[row * NMODEL + m0] = oA;
                out[row * NMODEL + m1] = oB;
            }
        }
    }
}

extern "C" void kernel_launch(void* const* d_in, const int* in_sizes, int n_in,
                              void* d_out, int out_size, void* d_ws, size_t ws_size,
                              hipStream_t stream) {
    const float* x     = (const float*)d_in[0];
    const float* W_in  = (const float*)d_in[1];
    const float* b_in  = (const float*)d_in[2];
    const float* W_h   = (const float*)d_in[3];
    const float* b_h   = (const float*)d_in[4];
    const float* W_out = (const float*)d_in[5];
    const float* b_out = (const float*)d_in[6];
    float* out = (float*)d_out;

    short* wib = (short*)d_ws;                       // 24*64*64*8 bf16 = 1.5 MB
    short* whb = wib + NMODEL * 64 * HID * 8;        // 24*5*8*64*8 bf16 = 0.94 MB

    const int N = in_sizes[0] / DIN;                 // 65536

    dg_convert<<<3072, 256, 0, stream>>>(W_in, W_h, wib, whb);
    dg_main<<<N / 64, 512, 0, stream>>>(x, wib, whb, b_in, b_h, W_out, b_out, out);
}

// Round 10
// 234.256 us; speedup vs baseline: 3.4794x; 3.4794x over previous
//
#include <hip/hip_runtime.h>
#include <hip/hip_bf16.h>

typedef __attribute__((ext_vector_type(8))) short short8;
typedef __attribute__((ext_vector_type(4))) float f32x4;
typedef __attribute__((ext_vector_type(4))) unsigned uint4v;

#define NMODEL 24
#define DIN    495
#define KP     512
#define HID    64
#define NLAY   5

__device__ __forceinline__ short bf16r(float f) {
    unsigned u = __float_as_uint(f);
    u += 0x7fffu + ((u >> 16) & 1u);          // round-to-nearest-even
    return (short)(u >> 16);
}
__device__ __forceinline__ float bf16f(short s) {
    return __uint_as_float(((unsigned)(unsigned short)s) << 16);
}
// packed f32->bf16: one VALU op for two elements (gfx950 v_cvt_pk_bf16_f32)
__device__ __forceinline__ unsigned pkbf16(float lo, float hi) {
    unsigned r;
    asm("v_cvt_pk_bf16_f32 %0, %1, %2" : "=v"(r) : "v"(lo), "v"(hi));
    return r;
}
// pack two f32x4 accumulator fragments into one MFMA B-fragment (short8)
__device__ __forceinline__ short8 pack2(f32x4 a, f32x4 b) {
    uint4v w;
    w[0] = pkbf16(a[0], a[1]);
    w[1] = pkbf16(a[2], a[3]);
    w[2] = pkbf16(b[0], b[1]);
    w[3] = pkbf16(b[2], b[3]);
    return __builtin_bit_cast(short8, w);
}

struct __attribute__((packed, aligned(4))) f4a { float v[4]; };

// ---------------------------------------------------------------------------
// Weight pre-conversion to bf16 in MFMA-fragment-friendly layouts.
//   wib[m][kb][hout][t]  = W_in[m][kb*8+t][hout]          (k padded 495->512)
//   whb[m][l][kb][hout][t] = W_h[m][l][pi(kb,t)][hout]    (pi bakes the C->B
//     lane-group relabeling of the hidden-in axis)
// ---------------------------------------------------------------------------
__global__ void dg_convert(const float* __restrict__ W_in,
                           const float* __restrict__ W_h,
                           short* __restrict__ wib, short* __restrict__ whb) {
    int idx = blockIdx.x * 256 + threadIdx.x;
    if (idx < NMODEL * 64 * HID * 8) {
        int t    = idx & 7;
        int hout = (idx >> 3) & 63;
        int kb   = (idx >> 9) & 63;
        int m    = idx >> 15;
        int k    = kb * 8 + t;
        float v  = (k < DIN) ? W_in[((size_t)m * DIN + k) * HID + hout] : 0.f;
        wib[idx] = bf16r(v);
    }
    if (idx < NMODEL * NLAY * 8 * HID * 8) {
        int t    = idx & 7;
        int hout = (idx >> 3) & 63;
        int kb   = (idx >> 9) & 7;     // kb = 4*s + g
        int ml   = idx >> 12;          // m*5 + l
        int pk   = 16 * (2 * (kb >> 2) + (t >> 2)) + 4 * (kb & 3) + (t & 3);
        float v  = W_h[((size_t)ml * HID + pk) * HID + hout];
        whb[idx] = bf16r(v);
    }
}

// ---------------------------------------------------------------------------
// Fused kernel. Block = 1024 threads (16 waves), 64 rows of x staged in LDS
// (bf16, XOR-swizzled). Compute body is byte-identical to the round-3
// passing kernel (VGPR 60, no scratch) — it fits the 8-waves/SIMD register
// class (<=64), so doubling the waves per block raises occupancy to
// 2 blocks/CU x 16 waves = 32 waves/CU = 8 waves/SIMD (2x round 3's TLP).
// launch_bounds(1024,4) keeps the allocator cap at 128 (NOT 64 — round 7
// showed forcing 64 triggers catastrophic scratch demotion); the natural
// allocation ~60 then yields 8 waves/SIMD at runtime. Wave mapping keeps
// rbase thread-CONSTANT (half = w&1) so LDS addresses stay loop-invariant,
// and waves 2k/2k+1 run the same models (paired weight streams in L1/L2).
// ---------------------------------------------------------------------------
__global__ __launch_bounds__(1024, 4) void dg_main(
    const float* __restrict__ x,
    const short* __restrict__ wib, const short* __restrict__ whb,
    const float* __restrict__ b_in, const float* __restrict__ b_h,
    const float* __restrict__ W_out, const float* __restrict__ b_out,
    float* __restrict__ out) {

    __shared__ short xs[64 * KP];            // 64 KB

    const int tid  = threadIdx.x;
    const int lane = tid & 63;
    const int w    = tid >> 6;               // wave 0..15
    const int lrow = lane & 15;
    const int g    = lane >> 4;              // lane group 0..3
    const int rowbase = blockIdx.x * 64;
    const int mgrp = w >> 1;                 // 0..7: model group (3 models)
    const int hf   = w & 1;                  // row half (thread-constant!)
    const int rbase = hf * 32;

    // ---- stage x tile -> LDS as bf16, swizzled, zero-padded k>=495 ----
    // wave w, iter i covers row i*16+w; lane covers k0 = lane*8 .. +7
    for (int i = 0; i < 4; ++i) {
        int r  = i * 16 + w;
        int k0 = lane * 8;
        const float* xr = x + (size_t)(rowbase + r) * DIN + k0;
        uint4v vw;
        if (k0 + 8 <= DIN) {                 // lanes 0..60: fast vector path
            f4a a = *(const f4a*)xr;
            f4a b = *(const f4a*)(xr + 4);
            vw[0] = pkbf16(a.v[0], a.v[1]);
            vw[1] = pkbf16(a.v[2], a.v[3]);
            vw[2] = pkbf16(b.v[0], b.v[1]);
            vw[3] = pkbf16(b.v[2], b.v[3]);
        } else {                             // lanes 61..63: guarded tail
            float f[8];
#pragma unroll
            for (int j = 0; j < 8; ++j) f[j] = (k0 + j < DIN) ? xr[j] : 0.f;
            vw[0] = pkbf16(f[0], f[1]);
            vw[1] = pkbf16(f[2], f[3]);
            vw[2] = pkbf16(f[4], f[5]);
            vw[3] = pkbf16(f[6], f[7]);
        }
        int byte = (r * (KP * 2) + k0 * 2) ^ ((r & 7) << 4);
        *(short8*)((char*)xs + byte) = __builtin_bit_cast(short8, vw);
    }
    __syncthreads();

    // ---- 3 models per wave (paired across row halves), no further sync ----
#pragma unroll 1
    for (int mi = 0; mi < 3; ++mi) {
        const int m = mgrp * 3 + mi;

        // ---------------- input projection: C[hout 64][row 32], K = 512
        f32x4 acc[4][2];                      // [icf(hout/16)][rf(row/16)]
#pragma unroll
        for (int a = 0; a < 4; ++a)
#pragma unroll
            for (int b = 0; b < 2; ++b) acc[a][b] = (f32x4)0.0f;

        const short8* wA = (const short8*)wib + (size_t)m * 64 * 64;
#pragma unroll 2
        for (int skt = 0; skt < 16; ++skt) {
            const int kb = skt * 4 + g;
            short8 afr[4], bfr[2];
#pragma unroll
            for (int icf = 0; icf < 4; ++icf)
                afr[icf] = wA[(size_t)kb * 64 + icf * 16 + lrow];
#pragma unroll
            for (int rf = 0; rf < 2; ++rf) {
                int r = rbase + rf * 16 + lrow;
                int byte = (r * (KP * 2) + skt * 64 + g * 16) ^ ((r & 7) << 4);
                bfr[rf] = *(const short8*)((const char*)xs + byte);
            }
#pragma unroll
            for (int icf = 0; icf < 4; ++icf)
#pragma unroll
                for (int rf = 0; rf < 2; ++rf)
                    acc[icf][rf] = __builtin_amdgcn_mfma_f32_16x16x32_bf16(
                        afr[icf], bfr[rf], acc[icf][rf], 0, 0, 0);
        }

        // + b_in  (h0 is NOT relu'd)
        const float* bi = b_in + m * HID;
#pragma unroll
        for (int icf = 0; icf < 4; ++icf) {
            f32x4 bv = *(const f32x4*)(bi + icf * 16 + g * 4);
#pragma unroll
            for (int rf = 0; rf < 2; ++rf) acc[icf][rf] += bv;
        }

        // pack h0 into B-fragments (also kept for the residual)
        short8 h0b[2][2];                     // [s][rf]
#pragma unroll
        for (int s = 0; s < 2; ++s)
#pragma unroll
            for (int rf = 0; rf < 2; ++rf)
                h0b[s][rf] = pack2(acc[2 * s][rf], acc[2 * s + 1][rf]);

        // ---------------- 5 hidden layers, all in registers
        const short8* wH = (const short8*)whb + (size_t)m * NLAY * 8 * 64;
        short8 hc[2][2];
#pragma unroll
        for (int s = 0; s < 2; ++s)
#pragma unroll
            for (int rf = 0; rf < 2; ++rf) hc[s][rf] = h0b[s][rf];

        f32x4 hacc[4][2];
#pragma unroll 1
        for (int l = 0; l < NLAY; ++l) {
#pragma unroll
            for (int a = 0; a < 4; ++a)
#pragma unroll
                for (int b = 0; b < 2; ++b) hacc[a][b] = (f32x4)0.0f;
#pragma unroll
            for (int s = 0; s < 2; ++s) {
                const int kb = 4 * s + g;
                short8 afr[4];
#pragma unroll
                for (int icf = 0; icf < 4; ++icf)
                    afr[icf] = wH[(size_t)(l * 8 + kb) * 64 + icf * 16 + lrow];
#pragma unroll
                for (int icf = 0; icf < 4; ++icf)
#pragma unroll
                    for (int rf = 0; rf < 2; ++rf)
                        hacc[icf][rf] = __builtin_amdgcn_mfma_f32_16x16x32_bf16(
                            afr[icf], hc[s][rf], hacc[icf][rf], 0, 0, 0);
            }
            // bias + relu
            const float* bh = b_h + (size_t)(m * NLAY + l) * HID;
#pragma unroll
            for (int icf = 0; icf < 4; ++icf) {
                f32x4 bv = *(const f32x4*)(bh + icf * 16 + g * 4);
#pragma unroll
                for (int rf = 0; rf < 2; ++rf)
#pragma unroll
                    for (int j = 0; j < 4; ++j)
                        hacc[icf][rf][j] = fmaxf(hacc[icf][rf][j] + bv[j], 0.f);
            }
            if (l != NLAY - 1) {
#pragma unroll
                for (int s = 0; s < 2; ++s)
#pragma unroll
                    for (int rf = 0; rf < 2; ++rf)
                        hc[s][rf] = pack2(hacc[2 * s][rf], hacc[2 * s + 1][rf]);
            }
        }

        // ---------------- residual: h += h0 (bf16-rounded h0, ~2^-9 rel err)
#pragma unroll
        for (int icf = 0; icf < 4; ++icf)
#pragma unroll
            for (int rf = 0; rf < 2; ++rf)
#pragma unroll
                for (int j = 0; j < 4; ++j)
                    hacc[icf][rf][j] += bf16f(h0b[icf >> 1][rf][(icf & 1) * 4 + j]);

        // ---------------- head: dot(h, W_out) + b_out, tanh, store
        const float* wo = W_out + m * HID;
        const float bo = b_out[m];
#pragma unroll
        for (int rf = 0; rf < 2; ++rf) {
            float s = 0.f;
#pragma unroll
            for (int icf = 0; icf < 4; ++icf) {
                f32x4 wv = *(const f32x4*)(wo + icf * 16 + g * 4);
#pragma unroll
                for (int j = 0; j < 4; ++j)
                    s += hacc[icf][rf][j] * wv[j];
            }
            s += __shfl_xor(s, 16);
            s += __shfl_xor(s, 32);
            s += bo;
            float e = __expf(2.f * s);                 // overflow-safe tanh
            float o = 1.f - 2.f / (e + 1.f);
            if (g == 0)
                out[(size_t)(rowbase + rbase + rf * 16 + lrow) * NMODEL + m] = o;
        }
    }
}

extern "C" void kernel_launch(void* const* d_in, const int* in_sizes, int n_in,
                              void* d_out, int out_size, void* d_ws, size_t ws_size,
                              hipStream_t stream) {
    const float* x     = (const float*)d_in[0];
    const float* W_in  = (const float*)d_in[1];
    const float* b_in  = (const float*)d_in[2];
    const float* W_h   = (const float*)d_in[3];
    const float* b_h   = (const float*)d_in[4];
    const float* W_out = (const float*)d_in[5];
    const float* b_out = (const float*)d_in[6];
    float* out = (float*)d_out;

    short* wib = (short*)d_ws;                       // 24*64*64*8 bf16 = 1.5 MB
    short* whb = wib + NMODEL * 64 * HID * 8;        // 24*5*8*64*8 bf16 = 0.94 MB

    const int N = in_sizes[0] / DIN;                 // 65536

    dg_convert<<<3072, 256, 0, stream>>>(W_in, W_h, wib, whb);
    dg_main<<<N / 64, 1024, 0, stream>>>(x, wib, whb, b_in, b_h, W_out, b_out, out);
}

// Round 11
// 218.734 us; speedup vs baseline: 3.7263x; 1.0710x over previous
//
#include <hip/hip_runtime.h>
#include <hip/hip_bf16.h>

typedef __attribute__((ext_vector_type(8))) short short8;
typedef __attribute__((ext_vector_type(4))) float f32x4;
typedef __attribute__((ext_vector_type(4))) unsigned uint4v;

#define NMODEL 24
#define DIN    495
#define KP     512
#define HID    64
#define NLAY   5

__device__ __forceinline__ short bf16r(float f) {
    unsigned u = __float_as_uint(f);
    u += 0x7fffu + ((u >> 16) & 1u);          // round-to-nearest-even
    return (short)(u >> 16);
}
__device__ __forceinline__ float bf16f(short s) {
    return __uint_as_float(((unsigned)(unsigned short)s) << 16);
}
// packed f32->bf16: one VALU op for two elements (gfx950 v_cvt_pk_bf16_f32)
__device__ __forceinline__ unsigned pkbf16(float lo, float hi) {
    unsigned r;
    asm("v_cvt_pk_bf16_f32 %0, %1, %2" : "=v"(r) : "v"(lo), "v"(hi));
    return r;
}
// pack two f32x4 accumulator fragments into one MFMA B-fragment (short8)
__device__ __forceinline__ short8 pack2(f32x4 a, f32x4 b) {
    uint4v w;
    w[0] = pkbf16(a[0], a[1]);
    w[1] = pkbf16(a[2], a[3]);
    w[2] = pkbf16(b[0], b[1]);
    w[3] = pkbf16(b[2], b[3]);
    return __builtin_bit_cast(short8, w);
}

struct __attribute__((packed, aligned(4))) f4a { float v[4]; };

// ---------------------------------------------------------------------------
// Weight pre-conversion to bf16 in MFMA-fragment-friendly layouts.
//   wib[m][kb][hout][t]  = W_in[m][kb*8+t][hout]          (k padded 495->512)
//   whb[m][l][kb][hout][t] = W_h[m][l][pi(kb,t)][hout]    (pi bakes the C->B
//     lane-group relabeling of the hidden-in axis)
// ---------------------------------------------------------------------------
__global__ void dg_convert(const float* __restrict__ W_in,
                           const float* __restrict__ W_h,
                           short* __restrict__ wib, short* __restrict__ whb) {
    int idx = blockIdx.x * 256 + threadIdx.x;
    if (idx < NMODEL * 64 * HID * 8) {
        int t    = idx & 7;
        int hout = (idx >> 3) & 63;
        int kb   = (idx >> 9) & 63;
        int m    = idx >> 15;
        int k    = kb * 8 + t;
        float v  = (k < DIN) ? W_in[((size_t)m * DIN + k) * HID + hout] : 0.f;
        wib[idx] = bf16r(v);
    }
    if (idx < NMODEL * NLAY * 8 * HID * 8) {
        int t    = idx & 7;
        int hout = (idx >> 3) & 63;
        int kb   = (idx >> 9) & 7;     // kb = 4*s + g
        int ml   = idx >> 12;          // m*5 + l
        int pk   = 16 * (2 * (kb >> 2) + (t >> 2)) + 4 * (kb & 3) + (t & 3);
        float v  = W_h[((size_t)ml * HID + pk) * HID + hout];
        whb[idx] = bf16r(v);
    }
}

// ---------------------------------------------------------------------------
// Fused kernel. Block = 512 threads (8 waves), 64 rows of x staged in LDS
// (bf16, XOR-swizzled). Each wave owns a 32-row half-tile (4x2 fragments)
// and runs 6 full models; waves PAIRED on the model index so weight streams
// merge in L1/L2. Occupancy is register-capped at 4 waves/SIMD (arch VGPR 60
// + ~64 AGPR accumulators = ~124 unified regs -> <=128 class; rounds 7/10
// proved geometry cannot raise it). THIS ROUND (isolated T5): s_setprio(1)
// around each MFMA cluster to decorrelate the wave convoy — all waves leave
// __syncthreads in lockstep and hit weight-load stalls simultaneously;
// priority asymmetry lets MFMA-ready waves preempt load-issuing ones.
// Body numerics byte-identical to round 3 (setprio is a pure hint).
// ---------------------------------------------------------------------------
__global__ __launch_bounds__(512, 4) void dg_main(
    const float* __restrict__ x,
    const short* __restrict__ wib, const short* __restrict__ whb,
    const float* __restrict__ b_in, const float* __restrict__ b_h,
    const float* __restrict__ W_out, const float* __restrict__ b_out,
    float* __restrict__ out) {

    __shared__ short xs[64 * KP];            // 64 KB

    const int tid  = threadIdx.x;
    const int lane = tid & 63;
    const int w    = tid >> 6;               // wave 0..7
    const int lrow = lane & 15;
    const int g    = lane >> 4;              // lane group 0..3
    const int rowbase = blockIdx.x * 64;
    const int pair = w >> 1;                 // 0..3: model group
    const int hf   = w & 1;                  // row half within the tile
    const int rbase = hf * 32;

    // ---- stage x tile -> LDS as bf16, swizzled, zero-padded k>=495 ----
    for (int i = 0; i < 8; ++i) {
        int r  = i * 8 + w;
        int k0 = lane * 8;
        const float* xr = x + (size_t)(rowbase + r) * DIN + k0;
        uint4v vw;
        if (k0 + 8 <= DIN) {                 // lanes 0..60: fast vector path
            f4a a = *(const f4a*)xr;
            f4a b = *(const f4a*)(xr + 4);
            vw[0] = pkbf16(a.v[0], a.v[1]);
            vw[1] = pkbf16(a.v[2], a.v[3]);
            vw[2] = pkbf16(b.v[0], b.v[1]);
            vw[3] = pkbf16(b.v[2], b.v[3]);
        } else {                             // lanes 61..63: guarded tail
            float f[8];
#pragma unroll
            for (int j = 0; j < 8; ++j) f[j] = (k0 + j < DIN) ? xr[j] : 0.f;
            vw[0] = pkbf16(f[0], f[1]);
            vw[1] = pkbf16(f[2], f[3]);
            vw[2] = pkbf16(f[4], f[5]);
            vw[3] = pkbf16(f[6], f[7]);
        }
        int byte = (r * (KP * 2) + k0 * 2) ^ ((r & 7) << 4);
        *(short8*)((char*)xs + byte) = __builtin_bit_cast(short8, vw);
    }
    __syncthreads();

    // ---- 6 models per wave (paired across row halves), no further sync ----
#pragma unroll 1
    for (int mi = 0; mi < 6; ++mi) {
        const int m = pair * 6 + mi;

        // ---------------- input projection: C[hout 64][row 32], K = 512
        f32x4 acc[4][2];                      // [icf(hout/16)][rf(row/16)]
#pragma unroll
        for (int a = 0; a < 4; ++a)
#pragma unroll
            for (int b = 0; b < 2; ++b) acc[a][b] = (f32x4)0.0f;

        const short8* wA = (const short8*)wib + (size_t)m * 64 * 64;
#pragma unroll 2
        for (int skt = 0; skt < 16; ++skt) {
            const int kb = skt * 4 + g;
            short8 afr[4], bfr[2];
#pragma unroll
            for (int icf = 0; icf < 4; ++icf)
                afr[icf] = wA[(size_t)kb * 64 + icf * 16 + lrow];
#pragma unroll
            for (int rf = 0; rf < 2; ++rf) {
                int r = rbase + rf * 16 + lrow;
                int byte = (r * (KP * 2) + skt * 64 + g * 16) ^ ((r & 7) << 4);
                bfr[rf] = *(const short8*)((const char*)xs + byte);
            }
            __builtin_amdgcn_s_setprio(1);
#pragma unroll
            for (int icf = 0; icf < 4; ++icf)
#pragma unroll
                for (int rf = 0; rf < 2; ++rf)
                    acc[icf][rf] = __builtin_amdgcn_mfma_f32_16x16x32_bf16(
                        afr[icf], bfr[rf], acc[icf][rf], 0, 0, 0);
            __builtin_amdgcn_s_setprio(0);
        }

        // + b_in  (h0 is NOT relu'd)
        const float* bi = b_in + m * HID;
#pragma unroll
        for (int icf = 0; icf < 4; ++icf) {
            f32x4 bv = *(const f32x4*)(bi + icf * 16 + g * 4);
#pragma unroll
            for (int rf = 0; rf < 2; ++rf) acc[icf][rf] += bv;
        }

        // pack h0 into B-fragments (also kept for the residual)
        short8 h0b[2][2];                     // [s][rf]
#pragma unroll
        for (int s = 0; s < 2; ++s)
#pragma unroll
            for (int rf = 0; rf < 2; ++rf)
                h0b[s][rf] = pack2(acc[2 * s][rf], acc[2 * s + 1][rf]);

        // ---------------- 5 hidden layers, all in registers
        const short8* wH = (const short8*)whb + (size_t)m * NLAY * 8 * 64;
        short8 hc[2][2];
#pragma unroll
        for (int s = 0; s < 2; ++s)
#pragma unroll
            for (int rf = 0; rf < 2; ++rf) hc[s][rf] = h0b[s][rf];

        f32x4 hacc[4][2];
#pragma unroll 1
        for (int l = 0; l < NLAY; ++l) {
#pragma unroll
            for (int a = 0; a < 4; ++a)
#pragma unroll
                for (int b = 0; b < 2; ++b) hacc[a][b] = (f32x4)0.0f;
#pragma unroll
            for (int s = 0; s < 2; ++s) {
                const int kb = 4 * s + g;
                short8 afr[4];
#pragma unroll
                for (int icf = 0; icf < 4; ++icf)
                    afr[icf] = wH[(size_t)(l * 8 + kb) * 64 + icf * 16 + lrow];
                __builtin_amdgcn_s_setprio(1);
#pragma unroll
                for (int icf = 0; icf < 4; ++icf)
#pragma unroll
                    for (int rf = 0; rf < 2; ++rf)
                        hacc[icf][rf] = __builtin_amdgcn_mfma_f32_16x16x32_bf16(
                            afr[icf], hc[s][rf], hacc[icf][rf], 0, 0, 0);
                __builtin_amdgcn_s_setprio(0);
            }
            // bias + relu
            const float* bh = b_h + (size_t)(m * NLAY + l) * HID;
#pragma unroll
            for (int icf = 0; icf < 4; ++icf) {
                f32x4 bv = *(const f32x4*)(bh + icf * 16 + g * 4);
#pragma unroll
                for (int rf = 0; rf < 2; ++rf)
#pragma unroll
                    for (int j = 0; j < 4; ++j)
                        hacc[icf][rf][j] = fmaxf(hacc[icf][rf][j] + bv[j], 0.f);
            }
            if (l != NLAY - 1) {
#pragma unroll
                for (int s = 0; s < 2; ++s)
#pragma unroll
                    for (int rf = 0; rf < 2; ++rf)
                        hc[s][rf] = pack2(hacc[2 * s][rf], hacc[2 * s + 1][rf]);
            }
        }

        // ---------------- residual: h += h0 (bf16-rounded h0, ~2^-9 rel err)
#pragma unroll
        for (int icf = 0; icf < 4; ++icf)
#pragma unroll
            for (int rf = 0; rf < 2; ++rf)
#pragma unroll
                for (int j = 0; j < 4; ++j)
                    hacc[icf][rf][j] += bf16f(h0b[icf >> 1][rf][(icf & 1) * 4 + j]);

        // ---------------- head: dot(h, W_out) + b_out, tanh, store
        const float* wo = W_out + m * HID;
        const float bo = b_out[m];
#pragma unroll
        for (int rf = 0; rf < 2; ++rf) {
            float s = 0.f;
#pragma unroll
            for (int icf = 0; icf < 4; ++icf) {
                f32x4 wv = *(const f32x4*)(wo + icf * 16 + g * 4);
#pragma unroll
                for (int j = 0; j < 4; ++j)
                    s += hacc[icf][rf][j] * wv[j];
            }
            s += __shfl_xor(s, 16);
            s += __shfl_xor(s, 32);
            s += bo;
            float e = __expf(2.f * s);                 // overflow-safe tanh
            float o = 1.f - 2.f / (e + 1.f);
            if (g == 0)
                out[(size_t)(rowbase + rbase + rf * 16 + lrow) * NMODEL + m] = o;
        }
    }
}

extern "C" void kernel_launch(void* const* d_in, const int* in_sizes, int n_in,
                              void* d_out, int out_size, void* d_ws, size_t ws_size,
                              hipStream_t stream) {
    const float* x     = (const float*)d_in[0];
    const float* W_in  = (const float*)d_in[1];
    const float* b_in  = (const float*)d_in[2];
    const float* W_h   = (const float*)d_in[3];
    const float* b_h   = (const float*)d_in[4];
    const float* W_out = (const float*)d_in[5];
    const float* b_out = (const float*)d_in[6];
    float* out = (float*)d_out;

    short* wib = (short*)d_ws;                       // 24*64*64*8 bf16 = 1.5 MB
    short* whb = wib + NMODEL * 64 * HID * 8;        // 24*5*8*64*8 bf16 = 0.94 MB

    const int N = in_sizes[0] / DIN;                 // 65536

    dg_convert<<<3072, 256, 0, stream>>>(W_in, W_h, wib, whb);
    dg_main<<<N / 64, 512, 0, stream>>>(x, wib, whb, b_in, b_h, W_out, b_out, out);
}